// Round 1
// baseline (825.232 us; speedup 1.0000x reference)
//
#include <hip/hip_runtime.h>
#include <stdint.h>

#define N_TOK 7200
#define N_PAD 7232      // 113*64
#define K_CODE 8912
#define K_PAD 8960      // 140*64
#define MID 256
#define C_DIM 768
#define INV_TEMP (1.0f/0.07f)
#define INV_ETEMP 100.0f
#define MARGIN 0.02f
#define EPS_N 1e-12f

typedef __attribute__((ext_vector_type(8))) short short8;   // 8 bf16 (4 VGPRs)
typedef __attribute__((ext_vector_type(4))) float f32x4;

__device__ __forceinline__ unsigned short f2bf(float f) {
    unsigned u = __float_as_uint(f);
    u += 0x7fffu + ((u >> 16) & 1u);   // round-to-nearest-even
    return (unsigned short)(u >> 16);
}
__device__ __forceinline__ float bf2f(unsigned short h) {
    return __uint_as_float(((unsigned)h) << 16);
}

// ---------------- init: zero accumulators (ws is poisoned 0xAA each call) ---
__global__ void k_init(float* ap_acc, int* used, float* acc4) {
    int i = blockIdx.x * 256 + threadIdx.x;
    if (i < K_CODE) { ap_acc[i] = 0.f; used[i] = 0; }
    if (i < 4) acc4[i] = 0.f;
}

// ---------------- W_down -> transposed bf16 hi/lo splits ---------------------
__global__ void k_wsplit(const float* __restrict__ W,
                         unsigned short* __restrict__ wt_h,
                         unsigned short* __restrict__ wt_l) {
    int i = blockIdx.x * 256 + threadIdx.x;
    if (i >= C_DIM * MID) return;
    int c = i / MID, t = i % MID;        // coalesced read over t
    float v = W[i];
    unsigned short h = f2bf(v);
    unsigned short l = f2bf(v - bf2f(h));
    wt_h[t * C_DIM + c] = h;             // W^T layout: [t][c]
    wt_l[t * C_DIM + c] = l;
}

// ---------------- embedding l2norm -> en (f32) + en_h (bf16) ----------------
__global__ void k_ennorm(const float* __restrict__ emb,
                         float* __restrict__ en,
                         unsigned short* __restrict__ en_h) {
    int n = blockIdx.x, t = threadIdx.x;
    float v = emb[n * MID + t];
    __shared__ float sb[256];
    sb[t] = v * v; __syncthreads();
    for (int s = 128; s > 0; s >>= 1) { if (t < s) sb[t] += sb[t + s]; __syncthreads(); }
    float nn = sqrtf(sb[0]);
    float o = v / fmaxf(nn, EPS_N);
    en[n * MID + t] = o;
    en_h[n * MID + t] = f2bf(o);
}

// ---------------- z = x @ W_down via bf16x3 MFMA (fp32-quality) -------------
// grid (4 over MID-tiles, 113 over token-tiles), 256 threads
__global__ __launch_bounds__(256) void k_zgemm(const float* __restrict__ x,
                                               const unsigned short* __restrict__ wt_h,
                                               const unsigned short* __restrict__ wt_l,
                                               float* __restrict__ zbuf) {
    __shared__ unsigned short ls[4 * 64 * 72];   // xh, xl, wh, wl: 64 rows x (64+8) bf16
    unsigned short* xh = ls;
    unsigned short* xl = ls + 64 * 72;
    unsigned short* wh = ls + 2 * 64 * 72;
    unsigned short* wl = ls + 3 * 64 * 72;
    int tid = threadIdx.x;
    int m0 = blockIdx.y * 64;
    int t0 = blockIdx.x * 64;
    int lane = tid & 63, wv = tid >> 6;
    int quad = lane >> 4, l15 = lane & 15;
    int mrow0 = (wv >> 1) * 32, ncol0 = (wv & 1) * 32;
    f32x4 acc[2][2] = {};

    for (int ch = 0; ch < 12; ch++) {
        int c0 = ch * 64;
        // stage x chunk [64 rows x 64 f32] -> bf16 hi/lo
        for (int it = 0; it < 4; it++) {
            int r = it * 16 + (tid >> 4);
            int cq = tid & 15;                       // float4 index
            float4 v = make_float4(0.f, 0.f, 0.f, 0.f);
            int gr = m0 + r;
            if (gr < N_TOK) v = ((const float4*)x)[(size_t)gr * (C_DIM / 4) + (c0 >> 2) + cq];
            unsigned short h0 = f2bf(v.x), h1 = f2bf(v.y), h2 = f2bf(v.z), h3 = f2bf(v.w);
            ushort4 hh = make_ushort4(h0, h1, h2, h3);
            ushort4 ll = make_ushort4(f2bf(v.x - bf2f(h0)), f2bf(v.y - bf2f(h1)),
                                      f2bf(v.z - bf2f(h2)), f2bf(v.w - bf2f(h3)));
            *((ushort4*)&xh[r * 72 + cq * 4]) = hh;
            *((ushort4*)&xl[r * 72 + cq * 4]) = ll;
        }
        // stage W^T chunk [64 t-rows x 64 c] hi/lo
        for (int it = 0; it < 2; it++) {
            int r = it * 32 + (tid >> 3);
            int cq = tid & 7;                         // uint4 index (8 bf16)
            uint4 vh = ((const uint4*)wt_h)[(size_t)(t0 + r) * (C_DIM / 8) + (c0 >> 3) + cq];
            uint4 vl = ((const uint4*)wt_l)[(size_t)(t0 + r) * (C_DIM / 8) + (c0 >> 3) + cq];
            *((uint4*)&wh[r * 72 + cq * 8]) = vh;
            *((uint4*)&wl[r * 72 + cq * 8]) = vl;
        }
        __syncthreads();
        for (int ks = 0; ks < 2; ks++) {
            int co = ks * 32 + quad * 8;
            short8 ah0 = *((const short8*)&xh[(mrow0 + l15) * 72 + co]);
            short8 ah1 = *((const short8*)&xh[(mrow0 + 16 + l15) * 72 + co]);
            short8 al0 = *((const short8*)&xl[(mrow0 + l15) * 72 + co]);
            short8 al1 = *((const short8*)&xl[(mrow0 + 16 + l15) * 72 + co]);
            short8 bh0 = *((const short8*)&wh[(ncol0 + l15) * 72 + co]);
            short8 bh1 = *((const short8*)&wh[(ncol0 + 16 + l15) * 72 + co]);
            short8 bl0 = *((const short8*)&wl[(ncol0 + l15) * 72 + co]);
            short8 bl1 = *((const short8*)&wl[(ncol0 + 16 + l15) * 72 + co]);
            acc[0][0] = __builtin_amdgcn_mfma_f32_16x16x32_bf16(ah0, bh0, acc[0][0], 0, 0, 0);
            acc[0][1] = __builtin_amdgcn_mfma_f32_16x16x32_bf16(ah0, bh1, acc[0][1], 0, 0, 0);
            acc[1][0] = __builtin_amdgcn_mfma_f32_16x16x32_bf16(ah1, bh0, acc[1][0], 0, 0, 0);
            acc[1][1] = __builtin_amdgcn_mfma_f32_16x16x32_bf16(ah1, bh1, acc[1][1], 0, 0, 0);
            acc[0][0] = __builtin_amdgcn_mfma_f32_16x16x32_bf16(ah0, bl0, acc[0][0], 0, 0, 0);
            acc[0][1] = __builtin_amdgcn_mfma_f32_16x16x32_bf16(ah0, bl1, acc[0][1], 0, 0, 0);
            acc[1][0] = __builtin_amdgcn_mfma_f32_16x16x32_bf16(ah1, bl0, acc[1][0], 0, 0, 0);
            acc[1][1] = __builtin_amdgcn_mfma_f32_16x16x32_bf16(ah1, bl1, acc[1][1], 0, 0, 0);
            acc[0][0] = __builtin_amdgcn_mfma_f32_16x16x32_bf16(al0, bh0, acc[0][0], 0, 0, 0);
            acc[0][1] = __builtin_amdgcn_mfma_f32_16x16x32_bf16(al0, bh1, acc[0][1], 0, 0, 0);
            acc[1][0] = __builtin_amdgcn_mfma_f32_16x16x32_bf16(al1, bh0, acc[1][0], 0, 0, 0);
            acc[1][1] = __builtin_amdgcn_mfma_f32_16x16x32_bf16(al1, bh1, acc[1][1], 0, 0, 0);
        }
        __syncthreads();
    }
    // epilogue: write z (unnormalized, bias added later)
    for (int i = 0; i < 2; i++)
        for (int j = 0; j < 2; j++)
            for (int r = 0; r < 4; r++) {
                int gr = m0 + mrow0 + i * 16 + quad * 4 + r;
                int gc = t0 + ncol0 + j * 16 + l15;
                if (gr < N_TOK) zbuf[(size_t)gr * MID + gc] = acc[i][j][r];
            }
}

// ---------------- z + b -> l2norm -> zn (in place) + zn_h -------------------
__global__ void k_znorm(float* __restrict__ zbuf, const float* __restrict__ b_down,
                        unsigned short* __restrict__ zn_h) {
    int n = blockIdx.x, t = threadIdx.x;
    float v = zbuf[(size_t)n * MID + t] + b_down[t];
    __shared__ float sb[256];
    sb[t] = v * v; __syncthreads();
    for (int s = 128; s > 0; s >>= 1) { if (t < s) sb[t] += sb[t + s]; __syncthreads(); }
    float nn = sqrtf(sb[0]);
    float o = v / fmaxf(nn, EPS_N);
    zbuf[(size_t)n * MID + t] = o;
    zn_h[(size_t)n * MID + t] = f2bf(o);
}

// ---------------- d = 2 - 2*zn@en^T via bf16 MFMA, into out1 region ---------
// grid (140 code-tiles, 113 token-tiles), 256 threads
__global__ __launch_bounds__(256) void k_dgemm(const unsigned short* __restrict__ zn_h,
                                               const unsigned short* __restrict__ en_h,
                                               float* __restrict__ dbuf) {
    __shared__ unsigned short ls[2 * 64 * 136];    // A,B: 64 rows x (128+8) bf16
    unsigned short* at = ls;
    unsigned short* bt = ls + 64 * 136;
    int tid = threadIdx.x;
    int m0 = blockIdx.y * 64, k0c = blockIdx.x * 64;
    int lane = tid & 63, wv = tid >> 6;
    int quad = lane >> 4, l15 = lane & 15;
    int mrow0 = (wv >> 1) * 32, ncol0 = (wv & 1) * 32;
    f32x4 acc[2][2] = {};

    for (int ch = 0; ch < 2; ch++) {
        int c0 = ch * 128;
        for (int it = 0; it < 4; it++) {
            int r = it * 16 + (tid >> 4);
            int cq = tid & 15;                        // uint4 index (8 bf16)
            uint4 va = ((const uint4*)zn_h)[(size_t)(m0 + r) * (MID / 8) + (c0 >> 3) + cq];
            uint4 vb = ((const uint4*)en_h)[(size_t)(k0c + r) * (MID / 8) + (c0 >> 3) + cq];
            *((uint4*)&at[r * 136 + cq * 8]) = va;
            *((uint4*)&bt[r * 136 + cq * 8]) = vb;
        }
        __syncthreads();
        for (int ks = 0; ks < 4; ks++) {
            int co = ks * 32 + quad * 8;
            short8 a0 = *((const short8*)&at[(mrow0 + l15) * 136 + co]);
            short8 a1 = *((const short8*)&at[(mrow0 + 16 + l15) * 136 + co]);
            short8 b0 = *((const short8*)&bt[(ncol0 + l15) * 136 + co]);
            short8 b1 = *((const short8*)&bt[(ncol0 + 16 + l15) * 136 + co]);
            acc[0][0] = __builtin_amdgcn_mfma_f32_16x16x32_bf16(a0, b0, acc[0][0], 0, 0, 0);
            acc[0][1] = __builtin_amdgcn_mfma_f32_16x16x32_bf16(a0, b1, acc[0][1], 0, 0, 0);
            acc[1][0] = __builtin_amdgcn_mfma_f32_16x16x32_bf16(a1, b0, acc[1][0], 0, 0, 0);
            acc[1][1] = __builtin_amdgcn_mfma_f32_16x16x32_bf16(a1, b1, acc[1][1], 0, 0, 0);
        }
        __syncthreads();
    }
    for (int i = 0; i < 2; i++)
        for (int j = 0; j < 2; j++)
            for (int r = 0; r < 4; r++) {
                int gr = m0 + mrow0 + i * 16 + quad * 4 + r;
                int gc = k0c + ncol0 + j * 16 + l15;
                if (gr < N_TOK && gc < K_CODE)
                    dbuf[(size_t)gr * K_CODE + gc] = 2.f - 2.f * acc[i][j][r];
            }
}

// ---------------- per-row: min + candidates + softmax sums ------------------
__global__ void k_rowstats(const float* __restrict__ dbuf,
                           float* __restrict__ rs_m, float* __restrict__ rs_ist,
                           float* __restrict__ rs_is1,
                           int* __restrict__ ccnt, int* __restrict__ cand,
                           float* __restrict__ acc4) {
    int n = blockIdx.x, t = threadIdx.x;
    const float* dr = dbuf + (size_t)n * K_CODE;
    float vmin = 3.4e38f; int imin = K_CODE;
    for (int k = t; k < K_CODE; k += 256) {
        float v = dr[k];
        if (v < vmin) { vmin = v; imin = k; }
    }
    __shared__ float sv[256]; __shared__ int si[256];
    sv[t] = vmin; si[t] = imin; __syncthreads();
    for (int s = 128; s > 0; s >>= 1) {
        if (t < s) {
            float ov = sv[t + s]; int oi = si[t + s];
            if (ov < sv[t] || (ov == sv[t] && oi < si[t])) { sv[t] = ov; si[t] = oi; }
        }
        __syncthreads();
    }
    float m = sv[0];
    __shared__ int lcnt; __shared__ int lcand[16];
    if (t == 0) lcnt = 0;
    __syncthreads();
    float s1 = 0.f, s2 = 0.f, st = 0.f;
    for (int k = t; k < K_CODE; k += 256) {
        float v = dr[k];
        if (v <= m + MARGIN) {
            int p = atomicAdd(&lcnt, 1);
            if (p < 16) lcand[p] = k;
        }
        float d = m - v;               // <= 0
        float te = d * INV_ETEMP;
        float e1 = __expf(te);
        s1 += e1; s2 += e1 * te;
        st += __expf(d * INV_TEMP);
    }
    // reduce the three sums (reuse sv with leading syncs)
    __syncthreads(); sv[t] = s1; __syncthreads();
    for (int s = 128; s > 0; s >>= 1) { if (t < s) sv[t] += sv[t + s]; __syncthreads(); }
    s1 = sv[0];
    __syncthreads(); sv[t] = s2; __syncthreads();
    for (int s = 128; s > 0; s >>= 1) { if (t < s) sv[t] += sv[t + s]; __syncthreads(); }
    s2 = sv[0];
    __syncthreads(); sv[t] = st; __syncthreads();
    for (int s = 128; s > 0; s >>= 1) { if (t < s) sv[t] += sv[t + s]; __syncthreads(); }
    st = sv[0];
    int cn = lcnt < 16 ? lcnt : 16;
    if (t == 0) {
        rs_m[n] = m; rs_ist[n] = 1.f / st; rs_is1[n] = 1.f / s1;
        ccnt[n] = cn;
        atomicAdd(&acc4[1], s2 / s1 - __logf(s1));   // sum over rows of sum(p*lp)
    }
    if (t < cn) cand[n * 16 + t] = lcand[t];
}

// ---------------- exact fp32 argmin refinement over candidates --------------
__global__ void k_refine(const float* __restrict__ zn, const float* __restrict__ en,
                         const int* __restrict__ ccnt, const int* __restrict__ cand,
                         int* __restrict__ idxb, int* __restrict__ used,
                         float* __restrict__ acc4) {
    int n = blockIdx.x * 4 + (threadIdx.x >> 6);
    int lane = threadIdx.x & 63;
    if (n >= N_TOK) return;
    int cnt = ccnt[n];
    float4 a = ((const float4*)(zn + (size_t)n * MID))[lane];
    float best = 3.4e38f; int bj = K_CODE;
    for (int c = 0; c < cnt; c++) {
        int j = cand[n * 16 + c];
        float4 b = ((const float4*)(en + (size_t)j * MID))[lane];
        float s = a.x * b.x + a.y * b.y + a.z * b.z + a.w * b.w;
        for (int off = 32; off > 0; off >>= 1) s += __shfl_down(s, off);
        s = __shfl(s, 0);
        float dist = 2.f - 2.f * s;
        if (dist < best || (dist == best && j < bj)) { best = dist; bj = j; }
    }
    float4 b = ((const float4*)(en + (size_t)bj * MID))[lane];
    float dx = b.x - a.x, dy = b.y - a.y, dz = b.z - a.z, dw = b.w - a.w;
    float sq = dx * dx + dy * dy + dz * dz + dw * dw;
    for (int off = 32; off > 0; off >>= 1) sq += __shfl_down(sq, off);
    if (lane == 0) {
        idxb[n] = bj;
        used[bj] = 1;
        atomicAdd(&acc4[0], sq);
    }
}

// ---------------- output 0: z_q_ste = en[idx] -------------------------------
__global__ void k_out0(const float* __restrict__ en, const int* __restrict__ idxb,
                       float* __restrict__ out0) {
    int n = blockIdx.x, t = threadIdx.x;
    int j = idxb[n];
    out0[(size_t)n * MID + t] = en[(size_t)j * MID + t];
}

// ---------------- probs (in place over d) + avg_probs accumulation ----------
// grid (35 k-chunks, 32 row-chunks of 225)
__global__ void k_probs(float* __restrict__ dbuf,
                        const float* __restrict__ rs_m, const float* __restrict__ rs_ist,
                        const float* __restrict__ rs_is1, float* __restrict__ ap_acc) {
    int k = blockIdx.x * 256 + threadIdx.x;
    int n0 = blockIdx.y * 225;
    bool ok = (k < K_CODE);
    float accE = 0.f;
    for (int n = n0; n < n0 + 225; n++) {
        float m = rs_m[n], ist = rs_ist[n], is1 = rs_is1[n];
        if (ok) {
            size_t off = (size_t)n * K_CODE + k;
            float v = dbuf[off];
            float d = m - v;
            dbuf[off] = __expf(d * INV_TEMP) * ist;
            accE += __expf(d * INV_ETEMP) * is1;
        }
    }
    if (ok) atomicAdd(&ap_acc[k], accE);
}

// ---------------- final scalars ---------------------------------------------
__global__ void k_scal(const int* __restrict__ used, const float* __restrict__ ap_acc,
                       const float* __restrict__ acc4, float* __restrict__ outs) {
    int t = threadIdx.x;
    float uSum = 0.f, aeSum = 0.f;
    for (int k = t; k < K_CODE; k += 256) {
        uSum += (float)used[k];
        float ap = ap_acc[k] * (1.0f / (float)N_TOK);
        aeSum += ap * __logf(ap + 1e-5f);
    }
    __shared__ float sb[256];
    sb[t] = uSum; __syncthreads();
    for (int s = 128; s > 0; s >>= 1) { if (t < s) sb[t] += sb[t + s]; __syncthreads(); }
    uSum = sb[0];
    __syncthreads(); sb[t] = aeSum; __syncthreads();
    for (int s = 128; s > 0; s >>= 1) { if (t < s) sb[t] += sb[t + s]; __syncthreads(); }
    aeSum = sb[0];
    if (t == 0) {
        outs[0] = uSum / (float)K_CODE;                       // code_book_usage
        float vq = acc4[0] / (float)((size_t)N_TOK * MID);
        outs[1] = vq;                                         // vq_loss
        outs[2] = vq;                                         // commit_loss (same fwd value)
        outs[3] = -(acc4[1] / (float)N_TOK) + aeSum;          // entropy_loss
    }
}

extern "C" void kernel_launch(void* const* d_in, const int* in_sizes, int n_in,
                              void* d_out, int out_size, void* d_ws, size_t ws_size,
                              hipStream_t stream) {
    const float* x   = (const float*)d_in[0];
    const float* W   = (const float*)d_in[1];
    const float* b   = (const float*)d_in[2];
    const float* emb = (const float*)d_in[3];

    float* out  = (float*)d_out;
    float* out0 = out;                                         // [7200*256]
    float* dbuf = out + (size_t)N_TOK * MID;                   // probs region reused for d
    float* outs = out + (size_t)N_TOK * MID + (size_t)N_TOK * K_CODE; // 4 scalars

    // workspace carve (all offsets 16B-aligned)
    char* w = (char*)d_ws;
    size_t off = 0;
    auto carve = [&](size_t bytes) { void* p = w + off; off += (bytes + 255) & ~(size_t)255; return p; };
    float*          zn    = (float*)         carve((size_t)N_PAD * MID * 4);
    float*          en    = (float*)         carve((size_t)K_PAD * MID * 4);
    unsigned short* zn_h  = (unsigned short*)carve((size_t)N_PAD * MID * 2);
    unsigned short* en_h  = (unsigned short*)carve((size_t)K_PAD * MID * 2);
    unsigned short* wt_h  = (unsigned short*)carve((size_t)MID * C_DIM * 2);
    unsigned short* wt_l  = (unsigned short*)carve((size_t)MID * C_DIM * 2);
    float*          rs_m  = (float*)         carve((size_t)N_TOK * 4);
    float*          rs_ist= (float*)         carve((size_t)N_TOK * 4);
    float*          rs_is1= (float*)         carve((size_t)N_TOK * 4);
    int*            ccnt  = (int*)           carve((size_t)N_TOK * 4);
    int*            cand  = (int*)           carve((size_t)N_TOK * 16 * 4);
    int*            idxb  = (int*)           carve((size_t)N_TOK * 4);
    float*          ap_acc= (float*)         carve((size_t)K_CODE * 4);
    int*            used  = (int*)           carve((size_t)K_CODE * 4);
    float*          acc4  = (float*)         carve(16);
    (void)ws_size; (void)in_sizes; (void)n_in; (void)out_size;

    k_init  <<<35, 256, 0, stream>>>(ap_acc, used, acc4);
    k_wsplit<<<(C_DIM * MID + 255) / 256, 256, 0, stream>>>(W, wt_h, wt_l);
    k_ennorm<<<K_CODE, 256, 0, stream>>>(emb, en, en_h);
    k_zgemm <<<dim3(4, 113), 256, 0, stream>>>(x, wt_h, wt_l, zn);
    k_znorm <<<N_TOK, 256, 0, stream>>>(zn, b, zn_h);
    k_dgemm <<<dim3(140, 113), 256, 0, stream>>>(zn_h, en_h, dbuf);
    k_rowstats<<<N_TOK, 256, 0, stream>>>(dbuf, rs_m, rs_ist, rs_is1, ccnt, cand, acc4);
    k_refine<<<N_TOK / 4, 256, 0, stream>>>(zn, en, ccnt, cand, idxb, used, acc4);
    k_out0  <<<N_TOK, 256, 0, stream>>>(en, idxb, out0);
    k_probs <<<dim3(35, 32), 256, 0, stream>>>(dbuf, rs_m, rs_ist, rs_is1, ap_acc);
    k_scal  <<<1, 256, 0, stream>>>(used, ap_acc, acc4, outs);
}

// Round 3
// 671.118 us; speedup vs baseline: 1.2296x; 1.2296x over previous
//
#include <hip/hip_runtime.h>
#include <stdint.h>

#define N_TOK 7200
#define N_PAD 7232      // 113*64
#define K_CODE 8912
#define K_PAD 8960      // 140*64
#define N_KT 140
#define MID 256
#define C_DIM 768
#define INV_TEMP (1.0f/0.07f)
#define INV_ETEMP 100.0f
#define MARGIN 0.02f
#define CAND_CAP 64
#define EPS_N 1e-12f

typedef __attribute__((ext_vector_type(8))) short short8;   // 8 bf16 (4 VGPRs)
typedef __attribute__((ext_vector_type(4))) float f32x4;

__device__ __forceinline__ unsigned short f2bf(float f) {
    unsigned u = __float_as_uint(f);
    u += 0x7fffu + ((u >> 16) & 1u);   // round-to-nearest-even
    return (unsigned short)(u >> 16);
}
__device__ __forceinline__ float bf2f(unsigned short h) {
    return __uint_as_float(((unsigned)h) << 16);
}

// ---------------- init: zero accumulators (ws is poisoned 0xAA each call) ---
__global__ void k_init(float* ap_acc, int* used, float* acc4, int* ccnt) {
    int i = blockIdx.x * 256 + threadIdx.x;
    if (i < K_CODE) { ap_acc[i] = 0.f; used[i] = 0; }
    if (i < N_TOK) ccnt[i] = 0;
    if (i < 4) acc4[i] = 0.f;
}

// ---------------- W_down -> transposed bf16 hi/lo splits ---------------------
__global__ void k_wsplit(const float* __restrict__ W,
                         unsigned short* __restrict__ wt_h,
                         unsigned short* __restrict__ wt_l) {
    int i = blockIdx.x * 256 + threadIdx.x;
    if (i >= C_DIM * MID) return;
    int c = i / MID, t = i % MID;
    float v = W[i];
    unsigned short h = f2bf(v);
    unsigned short l = f2bf(v - bf2f(h));
    wt_h[t * C_DIM + c] = h;
    wt_l[t * C_DIM + c] = l;
}

// ---------------- embedding l2norm -> en (f32) + en_h (bf16) ----------------
__global__ void k_ennorm(const float* __restrict__ emb,
                         float* __restrict__ en,
                         unsigned short* __restrict__ en_h) {
    int n = blockIdx.x, t = threadIdx.x;
    float v = emb[n * MID + t];
    __shared__ float sb[256];
    sb[t] = v * v; __syncthreads();
    for (int s = 128; s > 0; s >>= 1) { if (t < s) sb[t] += sb[t + s]; __syncthreads(); }
    float nn = sqrtf(sb[0]);
    float o = v / fmaxf(nn, EPS_N);
    en[n * MID + t] = o;
    en_h[n * MID + t] = f2bf(o);
}

// ---------------- z = x @ W_down via bf16x3 MFMA (fp32-quality) -------------
__global__ __launch_bounds__(256) void k_zgemm(const float* __restrict__ x,
                                               const unsigned short* __restrict__ wt_h,
                                               const unsigned short* __restrict__ wt_l,
                                               float* __restrict__ zbuf) {
    __shared__ unsigned short ls[4 * 64 * 72];
    unsigned short* xh = ls;
    unsigned short* xl = ls + 64 * 72;
    unsigned short* wh = ls + 2 * 64 * 72;
    unsigned short* wl = ls + 3 * 64 * 72;
    int tid = threadIdx.x;
    int m0 = blockIdx.y * 64;
    int t0 = blockIdx.x * 64;
    int lane = tid & 63, wv = tid >> 6;
    int quad = lane >> 4, l15 = lane & 15;
    int mrow0 = (wv >> 1) * 32, ncol0 = (wv & 1) * 32;
    f32x4 acc[2][2] = {};

    for (int ch = 0; ch < 12; ch++) {
        int c0 = ch * 64;
        for (int it = 0; it < 4; it++) {
            int r = it * 16 + (tid >> 4);
            int cq = tid & 15;
            float4 v = make_float4(0.f, 0.f, 0.f, 0.f);
            int gr = m0 + r;
            if (gr < N_TOK) v = ((const float4*)x)[(size_t)gr * (C_DIM / 4) + (c0 >> 2) + cq];
            unsigned short h0 = f2bf(v.x), h1 = f2bf(v.y), h2 = f2bf(v.z), h3 = f2bf(v.w);
            ushort4 hh = make_ushort4(h0, h1, h2, h3);
            ushort4 ll = make_ushort4(f2bf(v.x - bf2f(h0)), f2bf(v.y - bf2f(h1)),
                                      f2bf(v.z - bf2f(h2)), f2bf(v.w - bf2f(h3)));
            *((ushort4*)&xh[r * 72 + cq * 4]) = hh;
            *((ushort4*)&xl[r * 72 + cq * 4]) = ll;
        }
        for (int it = 0; it < 2; it++) {
            int r = it * 32 + (tid >> 3);
            int cq = tid & 7;
            uint4 vh = ((const uint4*)wt_h)[(size_t)(t0 + r) * (C_DIM / 8) + (c0 >> 3) + cq];
            uint4 vl = ((const uint4*)wt_l)[(size_t)(t0 + r) * (C_DIM / 8) + (c0 >> 3) + cq];
            *((uint4*)&wh[r * 72 + cq * 8]) = vh;
            *((uint4*)&wl[r * 72 + cq * 8]) = vl;
        }
        __syncthreads();
        for (int ks = 0; ks < 2; ks++) {
            int co = ks * 32 + quad * 8;
            short8 ah0 = *((const short8*)&xh[(mrow0 + l15) * 72 + co]);
            short8 ah1 = *((const short8*)&xh[(mrow0 + 16 + l15) * 72 + co]);
            short8 al0 = *((const short8*)&xl[(mrow0 + l15) * 72 + co]);
            short8 al1 = *((const short8*)&xl[(mrow0 + 16 + l15) * 72 + co]);
            short8 bh0 = *((const short8*)&wh[(ncol0 + l15) * 72 + co]);
            short8 bh1 = *((const short8*)&wh[(ncol0 + 16 + l15) * 72 + co]);
            short8 bl0 = *((const short8*)&wl[(ncol0 + l15) * 72 + co]);
            short8 bl1 = *((const short8*)&wl[(ncol0 + 16 + l15) * 72 + co]);
            acc[0][0] = __builtin_amdgcn_mfma_f32_16x16x32_bf16(ah0, bh0, acc[0][0], 0, 0, 0);
            acc[0][1] = __builtin_amdgcn_mfma_f32_16x16x32_bf16(ah0, bh1, acc[0][1], 0, 0, 0);
            acc[1][0] = __builtin_amdgcn_mfma_f32_16x16x32_bf16(ah1, bh0, acc[1][0], 0, 0, 0);
            acc[1][1] = __builtin_amdgcn_mfma_f32_16x16x32_bf16(ah1, bh1, acc[1][1], 0, 0, 0);
            acc[0][0] = __builtin_amdgcn_mfma_f32_16x16x32_bf16(ah0, bl0, acc[0][0], 0, 0, 0);
            acc[0][1] = __builtin_amdgcn_mfma_f32_16x16x32_bf16(ah0, bl1, acc[0][1], 0, 0, 0);
            acc[1][0] = __builtin_amdgcn_mfma_f32_16x16x32_bf16(ah1, bl0, acc[1][0], 0, 0, 0);
            acc[1][1] = __builtin_amdgcn_mfma_f32_16x16x32_bf16(ah1, bl1, acc[1][1], 0, 0, 0);
            acc[0][0] = __builtin_amdgcn_mfma_f32_16x16x32_bf16(al0, bh0, acc[0][0], 0, 0, 0);
            acc[0][1] = __builtin_amdgcn_mfma_f32_16x16x32_bf16(al0, bh1, acc[0][1], 0, 0, 0);
            acc[1][0] = __builtin_amdgcn_mfma_f32_16x16x32_bf16(al1, bh0, acc[1][0], 0, 0, 0);
            acc[1][1] = __builtin_amdgcn_mfma_f32_16x16x32_bf16(al1, bh1, acc[1][1], 0, 0, 0);
        }
        __syncthreads();
    }
    for (int i = 0; i < 2; i++)
        for (int j = 0; j < 2; j++)
            for (int r = 0; r < 4; r++) {
                int gr = m0 + mrow0 + i * 16 + quad * 4 + r;
                int gc = t0 + ncol0 + j * 16 + l15;
                if (gr < N_TOK) zbuf[(size_t)gr * MID + gc] = acc[i][j][r];
            }
}

// ---------------- z + b -> l2norm -> zn (in place) + zn_h -------------------
__global__ void k_znorm(float* __restrict__ zbuf, const float* __restrict__ b_down,
                        unsigned short* __restrict__ zn_h) {
    int n = blockIdx.x, t = threadIdx.x;
    float v = zbuf[(size_t)n * MID + t] + b_down[t];
    __shared__ float sb[256];
    sb[t] = v * v; __syncthreads();
    for (int s = 128; s > 0; s >>= 1) { if (t < s) sb[t] += sb[t + s]; __syncthreads(); }
    float nn = sqrtf(sb[0]);
    float o = v / fmaxf(nn, EPS_N);
    zbuf[(size_t)n * MID + t] = o;
    zn_h[(size_t)n * MID + t] = f2bf(o);
}

// ---------------- d-GEMM, two passes, no d materialization ------------------
// PASS 1: per-(row, col-tile) partials {min, st, s1, s2} -> part4
// PASS 2: probs -> out1, avg_probs column sums, element-level candidates
template<int PASS>
__global__ __launch_bounds__(256) void k_dpass(const unsigned short* __restrict__ zn_h,
                                               const unsigned short* __restrict__ en_h,
                                               float4* __restrict__ part4,
                                               const float* __restrict__ rs_m,
                                               const float* __restrict__ rs_ist,
                                               const float* __restrict__ rs_is1,
                                               float* __restrict__ ap_acc,
                                               float* __restrict__ out1,
                                               int* __restrict__ ccnt,
                                               int* __restrict__ cand) {
    __shared__ __align__(16) char smem[2 * 64 * 136 * 2];
    unsigned short* at = (unsigned short*)smem;
    unsigned short* bt = at + 64 * 136;
    int tid = threadIdx.x;
    int kt = blockIdx.x, mt = blockIdx.y;
    int m0 = mt * 64, k0c = kt * 64;
    int lane = tid & 63, wv = tid >> 6;
    int quad = lane >> 4, l15 = lane & 15;
    int mrow0 = (wv >> 1) * 32, ncol0 = (wv & 1) * 32;
    f32x4 acc[2][2] = {};

    for (int ch = 0; ch < 2; ch++) {
        int c0 = ch * 128;
        for (int it = 0; it < 4; it++) {
            int r = it * 16 + (tid >> 4);
            int cq = tid & 15;
            uint4 va = ((const uint4*)zn_h)[(size_t)(m0 + r) * (MID / 8) + (c0 >> 3) + cq];
            uint4 vb = ((const uint4*)en_h)[(size_t)(k0c + r) * (MID / 8) + (c0 >> 3) + cq];
            *((uint4*)&at[r * 136 + cq * 8]) = va;
            *((uint4*)&bt[r * 136 + cq * 8]) = vb;
        }
        __syncthreads();
        for (int ks = 0; ks < 4; ks++) {
            int co = ks * 32 + quad * 8;
            short8 a0 = *((const short8*)&at[(mrow0 + l15) * 136 + co]);
            short8 a1 = *((const short8*)&at[(mrow0 + 16 + l15) * 136 + co]);
            short8 b0 = *((const short8*)&bt[(ncol0 + l15) * 136 + co]);
            short8 b1 = *((const short8*)&bt[(ncol0 + 16 + l15) * 136 + co]);
            acc[0][0] = __builtin_amdgcn_mfma_f32_16x16x32_bf16(a0, b0, acc[0][0], 0, 0, 0);
            acc[0][1] = __builtin_amdgcn_mfma_f32_16x16x32_bf16(a0, b1, acc[0][1], 0, 0, 0);
            acc[1][0] = __builtin_amdgcn_mfma_f32_16x16x32_bf16(a1, b0, acc[1][0], 0, 0, 0);
            acc[1][1] = __builtin_amdgcn_mfma_f32_16x16x32_bf16(a1, b1, acc[1][1], 0, 0, 0);
        }
        __syncthreads();
    }

    // ---- epilogue: reuse smem as fp32 d-tile [64][68] + small arrays ----
    float* sd = (float*)smem;                  // 64*68*4 = 17408 B
    float* lm = sd + 64 * 68;                  // 64
    float* lt = lm + 64;                       // 64
    float* l1 = lt + 64;                       // 64
    float* colacc = l1 + 64;                   // 256

    if (PASS == 2) {
        if (tid < 64) {
            int gr = m0 + tid;
            bool okr = gr < N_TOK;
            lm[tid] = okr ? rs_m[gr] : 0.f;
            lt[tid] = okr ? rs_ist[gr] : 0.f;
            l1[tid] = okr ? rs_is1[gr] : 0.f;
        }
    }
    for (int i = 0; i < 2; i++)
        for (int j = 0; j < 2; j++)
            for (int r = 0; r < 4; r++) {
                int lr = mrow0 + i * 16 + quad * 4 + r;
                int lc = ncol0 + j * 16 + l15;
                int gc = k0c + lc;
                float dv = (gc < K_CODE) ? (2.f - 2.f * acc[i][j][r]) : 1e30f;
                sd[lr * 68 + lc] = dv;
            }
    __syncthreads();

    if (PASS == 1) {
        // 4 waves x 16 rows, 4 lanes/row, 16 values/lane
        int rloc = wv * 16 + (lane >> 2);
        const float* rowp = sd + rloc * 68 + (lane & 3) * 16;
        float vals[16];
        float vmin = 1e30f;
        #pragma unroll
        for (int i = 0; i < 16; i++) { vals[i] = rowp[i]; vmin = fminf(vmin, vals[i]); }
        vmin = fminf(vmin, __shfl_xor(vmin, 1));
        vmin = fminf(vmin, __shfl_xor(vmin, 2));
        float st = 0.f, s1 = 0.f, s2 = 0.f;
        #pragma unroll
        for (int i = 0; i < 16; i++) {
            float dd = vmin - vals[i];
            st += __expf(dd * INV_TEMP);
            float te = dd * INV_ETEMP;
            float e = __expf(te);
            s1 += e; s2 += e * te;
        }
        st += __shfl_xor(st, 1); st += __shfl_xor(st, 2);
        s1 += __shfl_xor(s1, 1); s1 += __shfl_xor(s1, 2);
        s2 += __shfl_xor(s2, 1); s2 += __shfl_xor(s2, 2);
        if ((lane & 3) == 0) {
            int gr = m0 + rloc;
            if (gr < N_TOK) part4[(size_t)gr * N_KT + kt] = make_float4(vmin, st, s1, s2);
        }
    } else {
        // phase A: avg_probs column sums
        int col = tid & 63, rq = tid >> 6;
        float ce = 0.f;
        #pragma unroll
        for (int r16 = 0; r16 < 16; r16++) {
            int lr = rq * 16 + r16;
            float dv = sd[lr * 68 + col];
            ce += __expf((lm[lr] - dv) * INV_ETEMP) * l1[lr];
        }
        colacc[rq * 64 + col] = ce;
        __syncthreads();
        if (tid < 64) {
            float s = colacc[tid] + colacc[64 + tid] + colacc[128 + tid] + colacc[192 + tid];
            int gc = k0c + tid;
            if (gc < K_CODE) atomicAdd(&ap_acc[gc], s);
        }
        // phase B: probs store (float4) + element-level candidate collection
        #pragma unroll
        for (int it = 0; it < 4; it++) {
            int idx = it * 256 + tid;
            int lr = idx >> 4, c4 = idx & 15;
            int gr = m0 + lr;
            if (gr >= N_TOK) continue;
            int gc = k0c + c4 * 4;
            if (gc >= K_CODE) continue;           // K_CODE % 4 == 0: fully in or out
            float4 v = *((const float4*)(sd + lr * 68 + c4 * 4));
            float mm = lm[lr], tt = lt[lr];
            float thr = mm + MARGIN;
            if (v.x <= thr) { int p = atomicAdd(&ccnt[gr], 1); if (p < CAND_CAP) cand[gr * CAND_CAP + p] = gc + 0; }
            if (v.y <= thr) { int p = atomicAdd(&ccnt[gr], 1); if (p < CAND_CAP) cand[gr * CAND_CAP + p] = gc + 1; }
            if (v.z <= thr) { int p = atomicAdd(&ccnt[gr], 1); if (p < CAND_CAP) cand[gr * CAND_CAP + p] = gc + 2; }
            if (v.w <= thr) { int p = atomicAdd(&ccnt[gr], 1); if (p < CAND_CAP) cand[gr * CAND_CAP + p] = gc + 3; }
            float4 p;
            p.x = __expf((mm - v.x) * INV_TEMP) * tt;
            p.y = __expf((mm - v.y) * INV_TEMP) * tt;
            p.z = __expf((mm - v.z) * INV_TEMP) * tt;
            p.w = __expf((mm - v.w) * INV_TEMP) * tt;
            *((float4*)(out1 + (size_t)gr * K_CODE + gc)) = p;
        }
    }
}

// ---------------- combine 140 tile-partials per row -------------------------
__global__ void k_combine(const float4* __restrict__ part4,
                          float* __restrict__ rs_m, float* __restrict__ rs_ist,
                          float* __restrict__ rs_is1,
                          float* __restrict__ acc4) {
    int sub = threadIdx.x >> 6;
    int row = blockIdx.x * 4 + sub;
    int l = threadIdx.x & 63;
    float4 pv[3];
    float m = 1e30f;
    #pragma unroll
    for (int c = 0; c < 3; c++) {
        int t = l + c * 64;
        pv[c] = (t < N_KT) ? part4[(size_t)row * N_KT + t] : make_float4(1e30f, 0.f, 0.f, 0.f);
        m = fminf(m, pv[c].x);
    }
    #pragma unroll
    for (int s = 1; s < 64; s <<= 1) m = fminf(m, __shfl_xor(m, s));
    float st = 0.f, s1 = 0.f, s2 = 0.f;
    #pragma unroll
    for (int c = 0; c < 3; c++) {
        float mb = pv[c].x;
        int t = l + c * 64;
        if (t < N_KT && mb < 1e29f) {
            float dT = (m - mb) * INV_TEMP;
            st += __expf(dT) * pv[c].y;
            float dE = (m - mb) * INV_ETEMP;
            float e = __expf(dE);
            s1 += e * pv[c].z;
            s2 += e * (pv[c].w + dE * pv[c].z);
        }
    }
    #pragma unroll
    for (int s = 1; s < 64; s <<= 1) {
        st += __shfl_xor(st, s);
        s1 += __shfl_xor(s1, s);
        s2 += __shfl_xor(s2, s);
    }
    if (l == 0) {
        rs_m[row] = m;
        rs_ist[row] = 1.f / st;
        rs_is1[row] = 1.f / s1;
        atomicAdd(&acc4[1], s2 / s1 - __logf(s1));
    }
}

// ---------------- exact fp32 argmin over element candidates -----------------
__global__ void k_refine(const float* __restrict__ zn, const float* __restrict__ en,
                         const int* __restrict__ ccnt, const int* __restrict__ cand,
                         int* __restrict__ idxb, int* __restrict__ used,
                         float* __restrict__ acc4) {
    int n = blockIdx.x * 4 + (threadIdx.x >> 6);
    int lane = threadIdx.x & 63;
    if (n >= N_TOK) return;
    int cnt = ccnt[n];
    if (cnt > CAND_CAP) cnt = CAND_CAP;
    float4 a = ((const float4*)(zn + (size_t)n * MID))[lane];
    float best = 1e30f; int bj = K_CODE;
    for (int c = 0; c < cnt; c++) {
        int code = cand[n * CAND_CAP + c];
        float4 b = ((const float4*)(en + (size_t)code * MID))[lane];
        float s = a.x * b.x + a.y * b.y + a.z * b.z + a.w * b.w;
        #pragma unroll
        for (int off = 1; off < 64; off <<= 1) s += __shfl_xor(s, off);
        float dist = 2.f - 2.f * s;
        if (dist < best || (dist == best && code < bj)) { best = dist; bj = code; }
    }
    float4 b = ((const float4*)(en + (size_t)bj * MID))[lane];
    float dx = b.x - a.x, dy = b.y - a.y, dz = b.z - a.z, dw = b.w - a.w;
    float sq = dx * dx + dy * dy + dz * dz + dw * dw;
    #pragma unroll
    for (int off = 32; off > 0; off >>= 1) sq += __shfl_down(sq, off);
    if (lane == 0) {
        idxb[n] = bj;
        used[bj] = 1;
        atomicAdd(&acc4[0], sq);
    }
}

// ---------------- output 0: z_q_ste = en[idx] -------------------------------
__global__ void k_out0(const float* __restrict__ en, const int* __restrict__ idxb,
                       float* __restrict__ out0) {
    int n = blockIdx.x, t = threadIdx.x;
    int j = idxb[n];
    out0[(size_t)n * MID + t] = en[(size_t)j * MID + t];
}

// ---------------- final scalars ---------------------------------------------
__global__ void k_scal(const int* __restrict__ used, const float* __restrict__ ap_acc,
                       const float* __restrict__ acc4, float* __restrict__ outs) {
    int t = threadIdx.x;
    float uSum = 0.f, aeSum = 0.f;
    for (int k = t; k < K_CODE; k += 256) {
        uSum += (float)used[k];
        float ap = ap_acc[k] * (1.0f / (float)N_TOK);
        aeSum += ap * __logf(ap + 1e-5f);
    }
    __shared__ float sb[256];
    sb[t] = uSum; __syncthreads();
    for (int s = 128; s > 0; s >>= 1) { if (t < s) sb[t] += sb[t + s]; __syncthreads(); }
    uSum = sb[0];
    __syncthreads(); sb[t] = aeSum; __syncthreads();
    for (int s = 128; s > 0; s >>= 1) { if (t < s) sb[t] += sb[t + s]; __syncthreads(); }
    aeSum = sb[0];
    if (t == 0) {
        outs[0] = uSum / (float)K_CODE;
        float vq = acc4[0] / (float)((size_t)N_TOK * MID);
        outs[1] = vq;
        outs[2] = vq;
        outs[3] = -(acc4[1] / (float)N_TOK) + aeSum;
    }
}

extern "C" void kernel_launch(void* const* d_in, const int* in_sizes, int n_in,
                              void* d_out, int out_size, void* d_ws, size_t ws_size,
                              hipStream_t stream) {
    const float* x   = (const float*)d_in[0];
    const float* W   = (const float*)d_in[1];
    const float* b   = (const float*)d_in[2];
    const float* emb = (const float*)d_in[3];

    float* out  = (float*)d_out;
    float* out0 = out;                                                  // [7200*256]
    float* out1 = out + (size_t)N_TOK * MID;                            // probs
    float* outs = out + (size_t)N_TOK * MID + (size_t)N_TOK * K_CODE;   // 4 scalars

    char* w = (char*)d_ws;
    size_t off = 0;
    auto carve = [&](size_t bytes) { void* p = w + off; off += (bytes + 255) & ~(size_t)255; return p; };
    float*          zn    = (float*)         carve((size_t)N_PAD * MID * 4);
    float*          en    = (float*)         carve((size_t)K_PAD * MID * 4);
    unsigned short* zn_h  = (unsigned short*)carve((size_t)N_PAD * MID * 2);
    unsigned short* en_h  = (unsigned short*)carve((size_t)K_PAD * MID * 2);
    unsigned short* wt_h  = (unsigned short*)carve((size_t)MID * C_DIM * 2);
    unsigned short* wt_l  = (unsigned short*)carve((size_t)MID * C_DIM * 2);
    float4*         part4 = (float4*)        carve((size_t)N_TOK * N_KT * 16);
    float*          rs_m  = (float*)         carve((size_t)N_TOK * 4);
    float*          rs_ist= (float*)         carve((size_t)N_TOK * 4);
    float*          rs_is1= (float*)         carve((size_t)N_TOK * 4);
    int*            ccnt  = (int*)           carve((size_t)N_TOK * 4);
    int*            cand  = (int*)           carve((size_t)N_TOK * CAND_CAP * 4);
    int*            idxb  = (int*)           carve((size_t)N_TOK * 4);
    float*          ap_acc= (float*)         carve((size_t)K_CODE * 4);
    int*            used  = (int*)           carve((size_t)K_CODE * 4);
    float*          acc4  = (float*)         carve(16);
    (void)ws_size; (void)in_sizes; (void)n_in; (void)out_size;

    k_init   <<<35, 256, 0, stream>>>(ap_acc, used, acc4, ccnt);
    k_wsplit <<<(C_DIM * MID + 255) / 256, 256, 0, stream>>>(W, wt_h, wt_l);
    k_ennorm <<<K_CODE, 256, 0, stream>>>(emb, en, en_h);
    k_zgemm  <<<dim3(4, 113), 256, 0, stream>>>(x, wt_h, wt_l, zn);
    k_znorm  <<<N_TOK, 256, 0, stream>>>(zn, b, zn_h);
    k_dpass<1><<<dim3(N_KT, 113), 256, 0, stream>>>(zn_h, en_h, part4, rs_m, rs_ist, rs_is1, ap_acc, out1, ccnt, cand);
    k_combine<<<N_TOK / 4, 256, 0, stream>>>(part4, rs_m, rs_ist, rs_is1, acc4);
    k_dpass<2><<<dim3(N_KT, 113), 256, 0, stream>>>(zn_h, en_h, part4, rs_m, rs_ist, rs_is1, ap_acc, out1, ccnt, cand);
    k_refine <<<N_TOK / 4, 256, 0, stream>>>(zn, en, ccnt, cand, idxb, used, acc4);
    k_out0   <<<N_TOK, 256, 0, stream>>>(en, idxb, out0);
    k_scal   <<<1, 256, 0, stream>>>(used, ap_acc, acc4, outs);
}